// Round 2
// baseline (727.866 us; speedup 1.0000x reference)
//
#include <hip/hip_runtime.h>

// out[t, :] = (1/32) * sum_j features[idx[t, j], :]
// features: [1M, 128] f32 (512 MB), idx: [100k, 32] i32, out: [100k, 128] f32
//
// Cache-window phasing: split the 1M rows into 4 windows of 262144 rows
// (134 MB each, fits L3=256MB with headroom). All waves sweep windows in the
// same order, accumulating per-target partial sums in registers, so repeated
// row reads within a window hit the Infinity Cache instead of HBM.

constexpr int D = 128;
constexpr int S = 32;
constexpr int D2 = D / 2;          // float2 per row = 64 = one wave
constexpr int T = 13;              // targets per wave (ceil(100000/8192))
constexpr int NPHASE = 4;
constexpr int PH_SHIFT = 18;       // 2^18 = 262144 rows per window
constexpr int N_WAVES = 8192;      // 2048 blocks * 4 waves

__global__ __launch_bounds__(256) void Aggregator_20710332301461_kernel(
    const float* __restrict__ feat,
    const int* __restrict__ idx,
    float* __restrict__ out,
    int n_targets)
{
    const int lane = threadIdx.x & 63;
    const int w = blockIdx.x * (blockDim.x >> 6) + (threadIdx.x >> 6);

    const float2* __restrict__ f2 = reinterpret_cast<const float2*>(feat);
    float2* __restrict__ o2 = reinterpret_cast<float2*>(out);

    // Per-wave targets: t = w + k*8192 (balanced: every wave gets 12 or 13).
    // Lane l (l<32) holds idx[t][l]; broadcast per-sample via shfl.
    int myidx[T];
    float ax[T], ay[T];
    #pragma unroll
    for (int k = 0; k < T; ++k) {
        const int t = w + k * N_WAVES;
        myidx[k] = 0;
        ax[k] = 0.f;
        ay[k] = 0.f;
        if (t < n_targets && lane < S) myidx[k] = idx[t * S + lane];
    }

    // Phase-major sweep: only gather rows whose index falls in this window.
    for (int ph = 0; ph < NPHASE; ++ph) {
        #pragma unroll
        for (int k = 0; k < T; ++k) {
            const int t = w + k * N_WAVES;
            if (t >= n_targets) continue;   // wave-uniform
            #pragma unroll 8
            for (int j = 0; j < S; ++j) {
                const int r = __shfl(myidx[k], j);   // wave-uniform row index
                if ((r >> PH_SHIFT) == ph) {
                    const float2 v = f2[(size_t)r * D2 + lane];
                    ax[k] += v.x;
                    ay[k] += v.y;
                }
            }
        }
    }

    #pragma unroll
    for (int k = 0; k < T; ++k) {
        const int t = w + k * N_WAVES;
        if (t < n_targets) {
            float2 res;
            res.x = ax[k] * (1.f / S);
            res.y = ay[k] * (1.f / S);
            o2[(size_t)t * D2 + lane] = res;
        }
    }
}

extern "C" void kernel_launch(void* const* d_in, const int* in_sizes, int n_in,
                              void* d_out, int out_size, void* d_ws, size_t ws_size,
                              hipStream_t stream) {
    const float* feat = (const float*)d_in[0];
    const int* idx = (const int*)d_in[1];
    float* out = (float*)d_out;

    const int n_targets = out_size / D;   // 100,000

    const int block = 256;                 // 4 waves/block
    const int grid = N_WAVES / (block / 64);  // 2048 blocks -> 8192 waves, all resident

    Aggregator_20710332301461_kernel<<<grid, block, 0, stream>>>(feat, idx, out, n_targets);
}

// Round 3
// 239.018 us; speedup vs baseline: 3.0452x; 3.0452x over previous
//
#include <hip/hip_runtime.h>

// out[t, :] = (1/32) * sum_j features[idx[t, j], :]
// features: [1M, 128] f32, idx: [100k, 32] i32, out: [100k, 128] f32
//
// Dual-target wave: lanes 0-31 own target t0, lanes 32-63 own t1.
// Each lane loads float4 (16 B), so one wave-load instruction moves 1 KB
// across two feature rows -> half the wave-load instructions of the float2
// version, double the bytes in flight per outstanding load.

constexpr int D = 128;
constexpr int S = 32;
constexpr int D4 = D / 4;          // float4 per row = 32 = one half-wave
constexpr int N_WAVES = 8192;      // 2048 blocks * 4 waves, all resident

__global__ __launch_bounds__(256) void Aggregator_20710332301461_kernel(
    const float* __restrict__ feat,
    const int* __restrict__ idx,
    float* __restrict__ out,
    int n_targets)
{
    const int lane = threadIdx.x & 63;
    const int half = lane >> 5;        // 0: target t0, 1: target t1
    const int sub = lane & 31;         // float4 slot within the row
    const int w = blockIdx.x * (blockDim.x >> 6) + (threadIdx.x >> 6);

    const float4* __restrict__ f4 = reinterpret_cast<const float4*>(feat);
    float4* __restrict__ o4 = reinterpret_cast<float4*>(out);

    const int n_pairs = (n_targets + 1) >> 1;

    for (int p = w; p < n_pairs; p += N_WAVES) {
        const int t = 2 * p + half;          // this half-wave's target
        const bool valid = (t < n_targets);

        // Lane l holds idx[t_half][sub]: one coalesced 256 B read per wave.
        int myidx = 0;
        if (valid) myidx = idx[t * S + sub];

        float4 acc = {0.f, 0.f, 0.f, 0.f};
        #pragma unroll
        for (int j = 0; j < S; ++j) {
            // Broadcast sample j's row index within this half-wave.
            const int r = __shfl(myidx, half * 32 + j);
            const float4 v = f4[(size_t)r * D4 + sub];
            acc.x += v.x;
            acc.y += v.y;
            acc.z += v.z;
            acc.w += v.w;
        }

        if (valid) {
            float4 res;
            res.x = acc.x * (1.f / S);
            res.y = acc.y * (1.f / S);
            res.z = acc.z * (1.f / S);
            res.w = acc.w * (1.f / S);
            o4[(size_t)t * D4 + sub] = res;
        }
    }
}

extern "C" void kernel_launch(void* const* d_in, const int* in_sizes, int n_in,
                              void* d_out, int out_size, void* d_ws, size_t ws_size,
                              hipStream_t stream) {
    const float* feat = (const float*)d_in[0];
    const int* idx = (const int*)d_in[1];
    float* out = (float*)d_out;

    const int n_targets = out_size / D;   // 100,000

    const int block = 256;                         // 4 waves/block
    const int grid = N_WAVES / (block / 64);       // 2048 blocks

    Aggregator_20710332301461_kernel<<<grid, block, 0, stream>>>(feat, idx, out, n_targets);
}